// Round 14
// baseline (464.048 us; speedup 1.0000x reference)
//
#include <hip/hip_runtime.h>

#define N_NODES 50000
#define N_EDGES 600000
#define N_GRAPHS 512
#define DIM 128
#define NLAYERS 4
#define NCLASSES 10
#define KPS 136   // padded LDS row stride in USHORTS (272 B, 16B-aligned)
#define NTILES 782            // ceil(50000/64)
#define GGRID (NTILES * 4)    // 3128 = 391*8 exactly

typedef __attribute__((ext_vector_type(8))) short short8;
typedef __attribute__((ext_vector_type(4))) float f32x4;

union Frag { short8 s; uint4 u; };

// ---- fp32 <-> bf16 (RNE) helpers ----
__device__ inline unsigned short f2bf(float v) {
    union { float f; unsigned u; } c; c.f = v;
    unsigned u = c.u;
    u += 0x7FFFu + ((u >> 16) & 1u);
    return (unsigned short)(u >> 16);
}
__device__ inline float bfu_lo(unsigned u) {
    union { float f; unsigned x; } c; c.x = u << 16; return c.f;
}
__device__ inline float bfu_hi(unsigned u) {
    union { float f; unsigned x; } c; c.x = u & 0xFFFF0000u; return c.f;
}
__device__ inline void addRow(float* acc, const uint4& v) {
    acc[0] += bfu_lo(v.x); acc[1] += bfu_hi(v.x);
    acc[2] += bfu_lo(v.y); acc[3] += bfu_hi(v.y);
    acc[4] += bfu_lo(v.z); acc[5] += bfu_hi(v.z);
    acc[6] += bfu_lo(v.w); acc[7] += bfu_hi(v.w);
}

// ---------------------------------------------------------------------------
// CSR build
// ---------------------------------------------------------------------------
__global__ __launch_bounds__(256) void hist_kernel(
    const int* __restrict__ dst, int* __restrict__ deg)
{
    int e = blockIdx.x * 256 + threadIdx.x;
    if (e >= N_EDGES) return;
    atomicAdd(&deg[dst[e]], 1);
}

__global__ __launch_bounds__(256) void scan1_kernel(
    const int* __restrict__ deg, int* __restrict__ bsum)
{
    __shared__ int red[256];
    int t = threadIdx.x;
    int i4 = blockIdx.x * 256 + t;
    int s = 0;
    if (i4 < 12500) {
        int4 v = ((const int4*)deg)[i4];
        s = v.x + v.y + v.z + v.w;
    }
    red[t] = s;
    __syncthreads();
    for (int off = 128; off > 0; off >>= 1) {
        if (t < off) red[t] += red[t + off];
        __syncthreads();
    }
    if (t == 0) bsum[blockIdx.x] = red[0];
}

__global__ __launch_bounds__(64) void scan2_kernel(int* __restrict__ bsum)
{
    __shared__ int sh[64];
    int t = threadIdx.x;
    sh[t] = (t < 49) ? bsum[t] : 0;
    __syncthreads();
    if (t == 0) {
        int run = 0;
        for (int i = 0; i < 49; i++) { int v = sh[i]; sh[i] = run; run += v; }
    }
    __syncthreads();
    if (t < 49) bsum[t] = sh[t];
}

__global__ __launch_bounds__(256) void scan3_kernel(
    const int* __restrict__ deg, const int* __restrict__ bsum,
    int* __restrict__ rowptr, int* __restrict__ cursor)
{
    __shared__ int red[256];
    int t = threadIdx.x;
    int i4 = blockIdx.x * 256 + t;
    int4 v = {0, 0, 0, 0};
    if (i4 < 12500) v = ((const int4*)deg)[i4];
    int s = v.x + v.y + v.z + v.w;
    red[t] = s;
    __syncthreads();
    for (int off = 1; off < 256; off <<= 1) {
        int val = (t >= off) ? red[t - off] : 0;
        __syncthreads();
        red[t] += val;
        __syncthreads();
    }
    int run = bsum[blockIdx.x] + (t ? red[t - 1] : 0);
    if (i4 < 12500) {
        int4 rp;
        rp.x = run; run += v.x;
        rp.y = run; run += v.y;
        rp.z = run; run += v.z;
        rp.w = run; run += v.w;
        ((int4*)rowptr)[i4] = rp;
        ((int4*)cursor)[i4] = rp;
    }
    if (blockIdx.x == 0 && t == 0) rowptr[N_NODES] = N_EDGES;
}

__global__ __launch_bounds__(256) void fill_kernel(
    const int* __restrict__ src, const int* __restrict__ dst,
    int* __restrict__ cursor, int* __restrict__ csr)
{
    int e = blockIdx.x * 256 + threadIdx.x;
    if (e >= N_EDGES) return;
    int p = atomicAdd(&cursor[dst[e]], 1);
    csr[p] = src[e];
}

__global__ __launch_bounds__(256) void bounds_kernel(
    const int* __restrict__ batch, int* __restrict__ gstart)
{
    int n = blockIdx.x * 256 + threadIdx.x;
    if (n >= N_NODES) return;
    int b = batch[n];
    int bp = (n == 0) ? -1 : batch[n - 1];
    for (int g = bp + 1; g <= b; g++) gstart[g] = n;
    if (n == N_NODES - 1)
        for (int g = b + 1; g <= N_GRAPHS; g++) gstart[g] = N_NODES;
}

// ---------------------------------------------------------------------------
// x -> bf16 packed
// ---------------------------------------------------------------------------
__global__ __launch_bounds__(256) void xconv_kernel(
    const float* __restrict__ x, unsigned int* __restrict__ xb)
{
    int idx = blockIdx.x * 256 + threadIdx.x;
    if (idx >= N_NODES * 32) return;
    float4 v = ((const float4*)x)[idx];
    uint2 o;
    o.x = (unsigned)f2bf(v.x) | ((unsigned)f2bf(v.y) << 16);
    o.y = (unsigned)f2bf(v.z) | ((unsigned)f2bf(v.w) << 16);
    ((uint2*)xb)[idx] = o;
}

// ---------------------------------------------------------------------------
// Pre-swizzle W1/W2 into MFMA B-fragment order, bf16 hi only.
// ---------------------------------------------------------------------------
__global__ __launch_bounds__(256) void wconv_kernel(
    const float* __restrict__ W1, const float* __restrict__ W2,
    unsigned short* __restrict__ whi)
{
    int idx = blockIdx.x * 256 + threadIdx.x;
    if (idx >= NLAYERS * 2 * 16384) return;
    int f   = idx & 16383;
    int w01 = (idx >> 14) & 1;
    int l   = idx >> 15;
    int j    = f & 7;
    int lane = (f >> 3) & 63;
    int cg   = (f >> 9) & 7;
    int ks   = f >> 12;
    int k = ks * 32 + (lane >> 4) * 8 + j;
    int n = cg * 16 + (lane & 15);
    const float* W = (w01 == 0 ? W1 : W2) + (size_t)l * 16384;
    whi[idx] = f2bf(W[k * 128 + n]);
}

// ---------------------------------------------------------------------------
// CHANNEL-SLICED pull-gather: block = 64 nodes x 32 channels (one slice).
// slice = (blockIdx & 7) >> 1 -> on round-robin XCD dispatch, slice s lands
// on XCDs {2s, 2s+1}; per-slice h working set = 3.2 MB < 4 MB XCD L2.
// Thread (m = t>>2, c = t&3): node tile*64+m, uint4 c of the 64B slice.
// z0 out = bf16 z0[n][128]. ~60 VGPR -> high occupancy at full ILP.
// ---------------------------------------------------------------------------
__global__ __launch_bounds__(256) void gather_slice_kernel(
    const unsigned int* __restrict__ hb,
    const int* __restrict__ rowptr, const int* __restrict__ csr,
    const float* __restrict__ epsP,
    unsigned short* __restrict__ z0)
{
    const int bid = blockIdx.x;
    const int slice = (bid & 7) >> 1;                 // 0..3
    const int tile  = (bid >> 3) * 2 + (bid & 1);     // 0..781
    const int t = threadIdx.x;
    const int m = t >> 2, c = t & 3;
    const int n = tile * 64 + m;
    if (n >= N_NODES) return;

    const uint4* hb4 = (const uint4*)hb;              // [n][16 uint4]
    const int coff = slice * 4 + c;                   // uint4 index in row

    float acc[8];
    {
        uint4 v = hb4[(size_t)n * 16 + coff];
        const float e1 = 1.0f + epsP[0];
        acc[0] = e1 * bfu_lo(v.x); acc[1] = e1 * bfu_hi(v.x);
        acc[2] = e1 * bfu_lo(v.y); acc[3] = e1 * bfu_hi(v.y);
        acc[4] = e1 * bfu_lo(v.z); acc[5] = e1 * bfu_hi(v.z);
        acc[6] = e1 * bfu_lo(v.w); acc[7] = e1 * bfu_hi(v.w);
    }
    int beg = rowptr[n], end = rowptr[n + 1];
    int e = beg;
    // 8-edge unroll, csr prefetch: 8 x 16B row-slice loads in flight
    if (e + 7 < end) {
        int s0 = csr[e],     s1 = csr[e + 1], s2 = csr[e + 2], s3 = csr[e + 3];
        int s4 = csr[e + 4], s5 = csr[e + 5], s6 = csr[e + 6], s7 = csr[e + 7];
        while (true) {
            uint4 v0 = hb4[(size_t)s0 * 16 + coff];
            uint4 v1 = hb4[(size_t)s1 * 16 + coff];
            uint4 v2 = hb4[(size_t)s2 * 16 + coff];
            uint4 v3 = hb4[(size_t)s3 * 16 + coff];
            uint4 v4 = hb4[(size_t)s4 * 16 + coff];
            uint4 v5 = hb4[(size_t)s5 * 16 + coff];
            uint4 v6 = hb4[(size_t)s6 * 16 + coff];
            uint4 v7 = hb4[(size_t)s7 * 16 + coff];
            int en = e + 8;
            bool more = (en + 7 < end);
            if (more) {
                s0 = csr[en];     s1 = csr[en + 1]; s2 = csr[en + 2]; s3 = csr[en + 3];
                s4 = csr[en + 4]; s5 = csr[en + 5]; s6 = csr[en + 6]; s7 = csr[en + 7];
            }
            addRow(acc, v0); addRow(acc, v1); addRow(acc, v2); addRow(acc, v3);
            addRow(acc, v4); addRow(acc, v5); addRow(acc, v6); addRow(acc, v7);
            e = en;
            if (!more) break;
        }
    }
    for (; e < end; e++) {
        uint4 v = hb4[(size_t)csr[e] * 16 + coff];
        addRow(acc, v);
    }
    // pack 8 bf16 -> one uint4 store (16B, 4-lane group = contiguous 64B)
    uint4 pk;
    pk.x = (unsigned)f2bf(acc[0]) | ((unsigned)f2bf(acc[1]) << 16);
    pk.y = (unsigned)f2bf(acc[2]) | ((unsigned)f2bf(acc[3]) << 16);
    pk.z = (unsigned)f2bf(acc[4]) | ((unsigned)f2bf(acc[5]) << 16);
    pk.w = (unsigned)f2bf(acc[6]) | ((unsigned)f2bf(acc[7]) << 16);
    *((uint4*)((unsigned int*)z0 + (size_t)n * 64 + (size_t)coff * 4)) = pk;
}

// ---------------------------------------------------------------------------
// MLP: z = relu(z0@W1+b1)@W2+b2 (bf16 A direct from global; B pre-swizzled;
// t via LDS) + bf16 z out + BN stats. 64-node tile, 4 waves.
// ---------------------------------------------------------------------------
__global__ __launch_bounds__(256) void mlp_kernel(
    const unsigned short* __restrict__ z0,
    unsigned short* __restrict__ z,
    const unsigned short* __restrict__ whi,
    const float* __restrict__ b1, const float* __restrict__ b2,
    float* __restrict__ stats)
{
    __shared__ unsigned short tpk[64 * KPS];   // 17408 B
    __shared__ float sums[1024];
    __shared__ float sqs[1024];

    const int t = threadIdx.x;
    const int lane = t & 63;
    const int w = t >> 6;
    const int wr = w & 1, wc = w >> 1;
    const int l15 = lane & 15, quad = lane >> 4;
    const int base = blockIdx.x * 64;

    // A row pointers (2 strips of 16), clamped
    int n0 = base + 32 * wr + l15;
    int n1 = n0 + 16;
    if (n0 >= N_NODES) n0 = N_NODES - 1;
    if (n1 >= N_NODES) n1 = N_NODES - 1;
    const unsigned short* r0 = z0 + (size_t)n0 * 128 + quad * 8;
    const unsigned short* r1 = z0 + (size_t)n1 * 128 + quad * 8;

    f32x4 acc[2][4];
    #pragma unroll
    for (int s = 0; s < 2; s++)
        #pragma unroll
        for (int i = 0; i < 4; i++) acc[s][i] = (f32x4){0.f, 0.f, 0.f, 0.f};

    // ================= GEMM1: z0 @ W1 (A direct global) =================
    #pragma unroll
    for (int kh = 0; kh < 2; kh++) {
        Frag bf[2][4];
        short8 a0[2], a1[2];
        #pragma unroll
        for (int kk = 0; kk < 2; kk++) {
            int ks = kh * 2 + kk;
            #pragma unroll
            for (int i = 0; i < 4; i++) {
                size_t woff = (size_t)(((ks * 8 + wc * 4 + i) * 64 + lane) * 8);
                bf[kk][i].s = *((const short8*)&whi[woff]);
            }
            a0[kk] = *((const short8*)(r0 + ks * 32));
            a1[kk] = *((const short8*)(r1 + ks * 32));
        }
        #pragma unroll
        for (int kk = 0; kk < 2; kk++) {
            #pragma unroll
            for (int i = 0; i < 4; i++) {
                acc[0][i] = __builtin_amdgcn_mfma_f32_16x16x32_bf16(a0[kk], bf[kk][i].s, acc[0][i], 0, 0, 0);
                acc[1][i] = __builtin_amdgcn_mfma_f32_16x16x32_bf16(a1[kk], bf[kk][i].s, acc[1][i], 0, 0, 0);
            }
        }
    }

    // ---- bias + relu -> t (bf16) in LDS ----
    #pragma unroll
    for (int i = 0; i < 4; i++) {
        int col = wc * 64 + i * 16 + l15;
        float bb = b1[col];
        #pragma unroll
        for (int s = 0; s < 2; s++) {
            #pragma unroll
            for (int r = 0; r < 4; r++) {
                int m = 32 * wr + 16 * s + quad * 4 + r;
                float v = fmaxf(acc[s][i][r] + bb, 0.f);
                tpk[m * KPS + col] = f2bf(v);
            }
            acc[s][i] = (f32x4){0.f, 0.f, 0.f, 0.f};
        }
    }
    __syncthreads();

    // ================= GEMM2: t @ W2 (A from LDS) =================
    const unsigned short* w2 = whi + 16384;
    const int arow0 = (32 * wr + l15) * KPS;
    const int arow1 = arow0 + 16 * KPS;
    #pragma unroll
    for (int kh = 0; kh < 2; kh++) {
        Frag bf[2][4];
        short8 a0[2], a1[2];
        #pragma unroll
        for (int kk = 0; kk < 2; kk++) {
            int ks = kh * 2 + kk;
            #pragma unroll
            for (int i = 0; i < 4; i++) {
                size_t woff = (size_t)(((ks * 8 + wc * 4 + i) * 64 + lane) * 8);
                bf[kk][i].s = *((const short8*)&w2[woff]);
            }
            a0[kk] = *((const short8*)&tpk[arow0 + ks * 32 + quad * 8]);
            a1[kk] = *((const short8*)&tpk[arow1 + ks * 32 + quad * 8]);
        }
        #pragma unroll
        for (int kk = 0; kk < 2; kk++) {
            #pragma unroll
            for (int i = 0; i < 4; i++) {
                acc[0][i] = __builtin_amdgcn_mfma_f32_16x16x32_bf16(a0[kk], bf[kk][i].s, acc[0][i], 0, 0, 0);
                acc[1][i] = __builtin_amdgcn_mfma_f32_16x16x32_bf16(a1[kk], bf[kk][i].s, acc[1][i], 0, 0, 0);
            }
        }
    }
    __syncthreads();   // tpk free for z staging

    // ---- bias; z-bf16 tile + stats partials ----
    {
        float colsum[4], colsq[4];
        #pragma unroll
        for (int i = 0; i < 4; i++) {
            int col = wc * 64 + i * 16 + l15;
            float bb = b2[col];
            float su = 0.f, q2 = 0.f;
            #pragma unroll
            for (int s = 0; s < 2; s++) {
                #pragma unroll
                for (int r = 0; r < 4; r++) {
                    int m = 32 * wr + 16 * s + quad * 4 + r;
                    int n = base + m;
                    float v = acc[s][i][r] + bb;
                    tpk[m * KPS + col] = f2bf(v);
                    if (n < N_NODES) { su += v; q2 += v * v; }
                }
            }
            colsum[i] = su; colsq[i] = q2;
        }
        #pragma unroll
        for (int i = 0; i < 4; i++) {
            sums[(w * 4 + i) * 64 + lane] = colsum[i];
            sqs [(w * 4 + i) * 64 + lane] = colsq[i];
        }
    }
    __syncthreads();

    // ---- coalesced z store (interleaved 64B per 4-lane group) ----
    {
        int m2 = t >> 2, c2 = t & 3;
        int n2 = base + m2;
        if (n2 < N_NODES) {
            const uint4* srcp = (const uint4*)(tpk + m2 * KPS);
            uint4* dstp = (uint4*)z + (size_t)n2 * 16;
            #pragma unroll
            for (int j = 0; j < 4; j++) dstp[j * 4 + c2] = srcp[j * 4 + c2];
        }
    }
    if (t < 128) {
        int c = t;
        int wcc = c >> 6, ci = (c >> 4) & 3, cl = c & 15;
        float s = 0.f, q2 = 0.f;
        #pragma unroll
        for (int wrr = 0; wrr < 2; wrr++) {
            int ww = wcc * 2 + wrr;
            #pragma unroll
            for (int u = 0; u < 4; u++) {
                int ln = cl + u * 16;
                s  += sums[(ww * 4 + ci) * 64 + ln];
                q2 += sqs [(ww * 4 + ci) * 64 + ln];
            }
        }
        unsafeAtomicAdd(&stats[c], s);
        unsafeAtomicAdd(&stats[128 + c], q2);
    }
}

// ---------------------------------------------------------------------------
// BN apply + ReLU + write h (bf16) + pool; z packed bf16.
// ---------------------------------------------------------------------------
__global__ __launch_bounds__(256) void bnpool_kernel(
    const unsigned int* __restrict__ z, const float* __restrict__ stats,
    const float* __restrict__ gamma, const float* __restrict__ beta,
    const int* __restrict__ gstart, unsigned int* __restrict__ hout,
    float* __restrict__ pools, int layer)
{
    __shared__ float red[8][128];
    const int g = blockIdx.x;
    const int t = threadIdx.x;
    const int q = t & 31, r = t >> 5;
    const int beg = gstart[g], end = gstart[g + 1];

    float4 s  = ((const float4*)stats)[q];
    float4 sq = ((const float4*)stats)[32 + q];
    float4 gm = ((const float4*)gamma)[q];
    float4 bt = ((const float4*)beta)[q];
    const float invN = 1.0f / (float)N_NODES;
    float m, vr;
    float4 scl, sh;
    m = s.x * invN; vr = sq.x * invN - m * m; scl.x = gm.x * rsqrtf(vr + 1e-5f); sh.x = bt.x - m * scl.x;
    m = s.y * invN; vr = sq.y * invN - m * m; scl.y = gm.y * rsqrtf(vr + 1e-5f); sh.y = bt.y - m * scl.y;
    m = s.z * invN; vr = sq.z * invN - m * m; scl.z = gm.z * rsqrtf(vr + 1e-5f); sh.z = bt.z - m * scl.z;
    m = s.w * invN; vr = sq.w * invN - m * m; scl.w = gm.w * rsqrtf(vr + 1e-5f); sh.w = bt.w - m * scl.w;

    float4 acc = {0.f, 0.f, 0.f, 0.f};
    for (int n = beg + r; n < end; n += 8) {
        uint2 zp = ((const uint2*)z)[(size_t)n * 32 + q];
        float4 hv;
        hv.x = fmaxf(bfu_lo(zp.x) * scl.x + sh.x, 0.f);
        hv.y = fmaxf(bfu_hi(zp.x) * scl.y + sh.y, 0.f);
        hv.z = fmaxf(bfu_lo(zp.y) * scl.z + sh.z, 0.f);
        hv.w = fmaxf(bfu_hi(zp.y) * scl.w + sh.w, 0.f);
        uint2 p;
        p.x = (unsigned)f2bf(hv.x) | ((unsigned)f2bf(hv.y) << 16);
        p.y = (unsigned)f2bf(hv.z) | ((unsigned)f2bf(hv.w) << 16);
        ((uint2*)hout)[(size_t)n * 32 + q] = p;
        acc.x += hv.x; acc.y += hv.y; acc.z += hv.z; acc.w += hv.w;
    }
    red[r][q * 4 + 0] = acc.x;
    red[r][q * 4 + 1] = acc.y;
    red[r][q * 4 + 2] = acc.z;
    red[r][q * 4 + 3] = acc.w;
    __syncthreads();
    if (t < 128) {
        float sm = 0.f;
        #pragma unroll
        for (int rr = 0; rr < 8; rr++) sm += red[rr][t];
        pools[(size_t)g * (DIM * NLAYERS) + (size_t)layer * DIM + t] = sm;
    }
}

// ---------------------------------------------------------------------------
// Final linear head: one wave per graph
// ---------------------------------------------------------------------------
__global__ __launch_bounds__(64) void final_kernel(
    const float* __restrict__ pools, const float* __restrict__ Wlin,
    const float* __restrict__ blin, float* __restrict__ out)
{
    int g = blockIdx.x;
    int lane = threadIdx.x;
    const float* xr = pools + (size_t)g * (DIM * NLAYERS);
    float a[NCLASSES];
    #pragma unroll
    for (int o = 0; o < NCLASSES; o++) a[o] = 0.f;
    for (int kk = 0; kk < DIM * NLAYERS; kk += 64) {
        float xv = xr[kk + lane];
        const float* wr = Wlin + (size_t)(kk + lane) * NCLASSES;
        #pragma unroll
        for (int o = 0; o < NCLASSES; o++) a[o] += xv * wr[o];
    }
    #pragma unroll
    for (int o = 0; o < NCLASSES; o++) {
        float v = a[o];
        #pragma unroll
        for (int off = 32; off > 0; off >>= 1) v += __shfl_down(v, off, 64);
        if (lane == 0) out[(size_t)g * NCLASSES + o] = v + blin[o];
    }
}

// ---------------------------------------------------------------------------
extern "C" void kernel_launch(void* const* d_in, const int* in_sizes, int n_in,
                              void* d_out, int out_size, void* d_ws, size_t ws_size,
                              hipStream_t stream)
{
    const float* x     = (const float*)d_in[0];
    const int*   src   = (const int*)d_in[1];
    const int*   dst   = ((const int*)d_in[1]) + N_EDGES;
    const int*   batch = (const int*)d_in[2];
    const float* W1    = (const float*)d_in[3];
    const float* b1    = (const float*)d_in[4];
    const float* W2    = (const float*)d_in[5];
    const float* b2    = (const float*)d_in[6];
    const float* eps   = (const float*)d_in[7];
    const float* gamma = (const float*)d_in[8];
    const float* beta  = (const float*)d_in[9];
    const float* Wlin  = (const float*)d_in[10];
    const float* blin  = (const float*)d_in[11];
    float* out = (float*)d_out;

    char* ws = (char*)d_ws;
    const size_t FEATH = (size_t)N_NODES * DIM * sizeof(unsigned short); // 12.8 MB
    size_t off = 0;
    unsigned int* buf_h = (unsigned int*)(ws + off); off += FEATH;       // bf16 h
    unsigned short* buf_z0 = (unsigned short*)(ws + off); off += FEATH;  // bf16 z0 (agg)
    unsigned short* buf_z  = (unsigned short*)(ws + off); off += FEATH;  // bf16 z (MLP out)
    float* pools  = (float*)(ws + off); off += (size_t)N_GRAPHS * DIM * NLAYERS * sizeof(float);
    float* stats  = (float*)(ws + off); off += (size_t)NLAYERS * 256 * sizeof(float);
    int*   deg    = (int*)(ws + off);   off += (size_t)N_NODES * sizeof(int);      // also "cursor"
    int*   rowptr = (int*)(ws + off);   off += (size_t)(N_NODES + 1) * sizeof(int) + 12;
    int*   csr    = (int*)(ws + off);   off += (size_t)N_EDGES * sizeof(int);
    int*   gstart = (int*)(ws + off);   off += 2064;
    int*   bsum   = (int*)(ws + off);   off += 208;
    unsigned short* whi = (unsigned short*)(ws + off); off += (size_t)NLAYERS * 2 * 16384 * 2;

    hipMemsetAsync(stats, 0, (size_t)NLAYERS * 256 * sizeof(float), stream);
    hipMemsetAsync(deg, 0, (size_t)N_NODES * sizeof(int), stream);

    // ---- once per call: CSR, bounds, x->bf16, weight pre-swizzle ----
    hist_kernel<<<(N_EDGES + 255) / 256, 256, 0, stream>>>(dst, deg);
    scan1_kernel<<<49, 256, 0, stream>>>(deg, bsum);
    scan2_kernel<<<1, 64, 0, stream>>>(bsum);
    scan3_kernel<<<49, 256, 0, stream>>>(deg, bsum, rowptr, deg /*cursor*/);
    fill_kernel<<<(N_EDGES + 255) / 256, 256, 0, stream>>>(src, dst, deg, csr);
    bounds_kernel<<<(N_NODES + 255) / 256, 256, 0, stream>>>(batch, gstart);
    xconv_kernel<<<(N_NODES * 32 + 255) / 256, 256, 0, stream>>>(x, buf_h);
    wconv_kernel<<<(NLAYERS * 2 * 16384 + 255) / 256, 256, 0, stream>>>(W1, W2, whi);

    for (int l = 0; l < NLAYERS; l++) {
        gather_slice_kernel<<<GGRID, 256, 0, stream>>>(
            buf_h, rowptr, csr, eps + l, buf_z0);
        mlp_kernel<<<NTILES, 256, 0, stream>>>(
            buf_z0, buf_z,
            whi + (size_t)l * 32768,
            b1 + (size_t)l * DIM, b2 + (size_t)l * DIM,
            stats + (size_t)l * 256);
        bnpool_kernel<<<N_GRAPHS, 256, 0, stream>>>(
            (const unsigned int*)buf_z, stats + (size_t)l * 256,
            gamma + (size_t)l * DIM, beta + (size_t)l * DIM,
            gstart, buf_h, pools, l);
    }
    final_kernel<<<N_GRAPHS, 64, 0, stream>>>(pools, Wlin, blin, out);
}

// Round 15
// 404.387 us; speedup vs baseline: 1.1475x; 1.1475x over previous
//
#include <hip/hip_runtime.h>

#define N_NODES 50000
#define N_EDGES 600000
#define N_GRAPHS 512
#define DIM 128
#define NLAYERS 4
#define NCLASSES 10
#define KPS 136   // padded LDS row stride in USHORTS (272 B, 16B-aligned)

typedef __attribute__((ext_vector_type(8))) short short8;
typedef __attribute__((ext_vector_type(4))) float f32x4;

union Frag { short8 s; uint4 u; };

// ---- fp32 <-> bf16 (RNE) helpers ----
__device__ inline unsigned short f2bf(float v) {
    union { float f; unsigned u; } c; c.f = v;
    unsigned u = c.u;
    u += 0x7FFFu + ((u >> 16) & 1u);
    return (unsigned short)(u >> 16);
}
__device__ inline float bfu_lo(unsigned u) {
    union { float f; unsigned x; } c; c.x = u << 16; return c.f;
}
__device__ inline float bfu_hi(unsigned u) {
    union { float f; unsigned x; } c; c.x = u & 0xFFFF0000u; return c.f;
}
__device__ inline void addRow(float* acc, const uint4& v) {
    acc[0] += bfu_lo(v.x); acc[1] += bfu_hi(v.x);
    acc[2] += bfu_lo(v.y); acc[3] += bfu_hi(v.y);
    acc[4] += bfu_lo(v.z); acc[5] += bfu_hi(v.z);
    acc[6] += bfu_lo(v.w); acc[7] += bfu_hi(v.w);
}

// ---------------------------------------------------------------------------
// CSR build
// ---------------------------------------------------------------------------
__global__ __launch_bounds__(256) void hist_kernel(
    const int* __restrict__ dst, int* __restrict__ deg)
{
    int e = blockIdx.x * 256 + threadIdx.x;
    if (e >= N_EDGES) return;
    atomicAdd(&deg[dst[e]], 1);
}

__global__ __launch_bounds__(256) void scan1_kernel(
    const int* __restrict__ deg, int* __restrict__ bsum)
{
    __shared__ int red[256];
    int t = threadIdx.x;
    int i4 = blockIdx.x * 256 + t;
    int s = 0;
    if (i4 < 12500) {
        int4 v = ((const int4*)deg)[i4];
        s = v.x + v.y + v.z + v.w;
    }
    red[t] = s;
    __syncthreads();
    for (int off = 128; off > 0; off >>= 1) {
        if (t < off) red[t] += red[t + off];
        __syncthreads();
    }
    if (t == 0) bsum[blockIdx.x] = red[0];
}

__global__ __launch_bounds__(64) void scan2_kernel(int* __restrict__ bsum)
{
    __shared__ int sh[64];
    int t = threadIdx.x;
    sh[t] = (t < 49) ? bsum[t] : 0;
    __syncthreads();
    if (t == 0) {
        int run = 0;
        for (int i = 0; i < 49; i++) { int v = sh[i]; sh[i] = run; run += v; }
    }
    __syncthreads();
    if (t < 49) bsum[t] = sh[t];
}

__global__ __launch_bounds__(256) void scan3_kernel(
    const int* __restrict__ deg, const int* __restrict__ bsum,
    int* __restrict__ rowptr, int* __restrict__ cursor)
{
    __shared__ int red[256];
    int t = threadIdx.x;
    int i4 = blockIdx.x * 256 + t;
    int4 v = {0, 0, 0, 0};
    if (i4 < 12500) v = ((const int4*)deg)[i4];
    int s = v.x + v.y + v.z + v.w;
    red[t] = s;
    __syncthreads();
    for (int off = 1; off < 256; off <<= 1) {
        int val = (t >= off) ? red[t - off] : 0;
        __syncthreads();
        red[t] += val;
        __syncthreads();
    }
    int run = bsum[blockIdx.x] + (t ? red[t - 1] : 0);
    if (i4 < 12500) {
        int4 rp;
        rp.x = run; run += v.x;
        rp.y = run; run += v.y;
        rp.z = run; run += v.z;
        rp.w = run; run += v.w;
        ((int4*)rowptr)[i4] = rp;
        ((int4*)cursor)[i4] = rp;
    }
    if (blockIdx.x == 0 && t == 0) rowptr[N_NODES] = N_EDGES;
}

__global__ __launch_bounds__(256) void fill_kernel(
    const int* __restrict__ src, const int* __restrict__ dst,
    int* __restrict__ cursor, int* __restrict__ csr)
{
    int e = blockIdx.x * 256 + threadIdx.x;
    if (e >= N_EDGES) return;
    int p = atomicAdd(&cursor[dst[e]], 1);
    csr[p] = src[e];
}

// ---------------------------------------------------------------------------
// Fused prep: graph bounds + x->bf16 + W pre-swizzle + stats zero.
// Block ranges: [0,196) bounds | [196,6446) xconv | [6446,6958) wconv | 6958 stats.
// ---------------------------------------------------------------------------
__global__ __launch_bounds__(256) void prep_kernel(
    const int* __restrict__ batch, int* __restrict__ gstart,
    const float* __restrict__ x, unsigned int* __restrict__ xb,
    const float* __restrict__ W1, const float* __restrict__ W2,
    unsigned short* __restrict__ whi, float* __restrict__ stats)
{
    int b = blockIdx.x;
    int t = threadIdx.x;
    if (b < 196) {
        int n = b * 256 + t;
        if (n >= N_NODES) return;
        int bb = batch[n];
        int bp = (n == 0) ? -1 : batch[n - 1];
        for (int g = bp + 1; g <= bb; g++) gstart[g] = n;
        if (n == N_NODES - 1)
            for (int g = bb + 1; g <= N_GRAPHS; g++) gstart[g] = N_NODES;
    } else if (b < 6446) {
        int idx = (b - 196) * 256 + t;
        if (idx >= N_NODES * 32) return;
        float4 v = ((const float4*)x)[idx];
        uint2 o;
        o.x = (unsigned)f2bf(v.x) | ((unsigned)f2bf(v.y) << 16);
        o.y = (unsigned)f2bf(v.z) | ((unsigned)f2bf(v.w) << 16);
        ((uint2*)xb)[idx] = o;
    } else if (b < 6958) {
        int idx = (b - 6446) * 256 + t;     // < 131072 exactly
        int f   = idx & 16383;
        int w01 = (idx >> 14) & 1;
        int l   = idx >> 15;
        int j    = f & 7;
        int lane = (f >> 3) & 63;
        int cg   = (f >> 9) & 7;
        int ks   = f >> 12;
        int k = ks * 32 + (lane >> 4) * 8 + j;
        int n = cg * 16 + (lane & 15);
        const float* W = (w01 == 0 ? W1 : W2) + (size_t)l * 16384;
        whi[idx] = f2bf(W[k * 128 + n]);
    } else {
        #pragma unroll
        for (int i = 0; i < 4; i++) stats[i * 256 + t] = 0.f;
    }
}

// ---------------------------------------------------------------------------
// FUSED GIN layer: pull-gather -> LDS (bf16) -> GEMM1 -> relu -> GEMM2 ->
// bf16 z + BN stats. A plain bf16; B bf16 (pre-swizzled hi).
// Gather: thread c owns INTERLEAVED uint4s {c,c+4,c+8,c+12} of each row ->
// each load instruction's 4-lane node-group reads a contiguous 64B block.
// ---------------------------------------------------------------------------
__global__ __launch_bounds__(256) void gin_layer_kernel(
    const unsigned int* __restrict__ hb,
    const int* __restrict__ rowptr, const int* __restrict__ csr,
    const float* __restrict__ epsP,
    unsigned short* __restrict__ z,
    const unsigned short* __restrict__ whi,
    const float* __restrict__ b1, const float* __restrict__ b2,
    float* __restrict__ stats)
{
    __shared__ unsigned short tpk[64 * KPS];   // 17408 B
    __shared__ float sums[1024];
    __shared__ float sqs[1024];

    const int t = threadIdx.x;
    const int lane = t & 63;
    const int w = t >> 6;
    const int wr = w & 1, wc = w >> 1;
    const int l15 = lane & 15, quad = lane >> 4;
    const int base = blockIdx.x * 64;

    // ---------------- Phase A: fused pull-aggregation ----------------
    {
        const int m = t >> 2;
        const int c = t & 3;
        const int n = base + m;
        const uint4* hb4 = (const uint4*)hb;
        float acc[32];
        #pragma unroll
        for (int i = 0; i < 32; i++) acc[i] = 0.f;
        if (n < N_NODES) {
            const float e1 = 1.0f + epsP[0];
            const uint4* self = hb4 + (size_t)n * 16 + c;
            #pragma unroll
            for (int j = 0; j < 4; j++) {
                uint4 v = self[j * 4];
                float* a = acc + j * 8;
                a[0] = e1 * bfu_lo(v.x); a[1] = e1 * bfu_hi(v.x);
                a[2] = e1 * bfu_lo(v.y); a[3] = e1 * bfu_hi(v.y);
                a[4] = e1 * bfu_lo(v.z); a[5] = e1 * bfu_hi(v.z);
                a[6] = e1 * bfu_lo(v.w); a[7] = e1 * bfu_hi(v.w);
            }
            int beg = rowptr[n], end = rowptr[n + 1];
            int e = beg;
            if (e + 3 < end) {
                int s0 = csr[e], s1 = csr[e + 1], s2 = csr[e + 2], s3 = csr[e + 3];
                while (true) {
                    const uint4* r0 = hb4 + (size_t)s0 * 16 + c;
                    const uint4* r1 = hb4 + (size_t)s1 * 16 + c;
                    const uint4* r2 = hb4 + (size_t)s2 * 16 + c;
                    const uint4* r3 = hb4 + (size_t)s3 * 16 + c;
                    uint4 v00 = r0[0], v01 = r0[4], v02 = r0[8], v03 = r0[12];
                    uint4 v10 = r1[0], v11 = r1[4], v12 = r1[8], v13 = r1[12];
                    uint4 v20 = r2[0], v21 = r2[4], v22 = r2[8], v23 = r2[12];
                    uint4 v30 = r3[0], v31 = r3[4], v32 = r3[8], v33 = r3[12];
                    int en = e + 4;
                    bool more = (en + 3 < end);
                    if (more) {
                        s0 = csr[en]; s1 = csr[en + 1];
                        s2 = csr[en + 2]; s3 = csr[en + 3];
                    }
                    addRow(acc + 0, v00); addRow(acc + 8, v01); addRow(acc + 16, v02); addRow(acc + 24, v03);
                    addRow(acc + 0, v10); addRow(acc + 8, v11); addRow(acc + 16, v12); addRow(acc + 24, v13);
                    addRow(acc + 0, v20); addRow(acc + 8, v21); addRow(acc + 16, v22); addRow(acc + 24, v23);
                    addRow(acc + 0, v30); addRow(acc + 8, v31); addRow(acc + 16, v32); addRow(acc + 24, v33);
                    e = en;
                    if (!more) break;
                }
            }
            for (; e < end; e++) {
                int s0 = csr[e];
                const uint4* r0 = hb4 + (size_t)s0 * 16 + c;
                uint4 a0 = r0[0], a1 = r0[4], a2 = r0[8], a3 = r0[12];
                addRow(acc + 0, a0);  addRow(acc + 8, a1);
                addRow(acc + 16, a2); addRow(acc + 24, a3);
            }
        }
        // pack bf16 (hi only) into A-layout LDS; 4 x 16B stores
        #pragma unroll
        for (int j = 0; j < 4; j++) {
            union { short8 s; unsigned short u[8]; } pk;
            #pragma unroll
            for (int i = 0; i < 8; i++) pk.u[i] = f2bf(acc[j * 8 + i]);
            *((short8*)&tpk[m * KPS + j * 32 + c * 8]) = pk.s;
        }
    }
    __syncthreads();

    f32x4 acc[2][4];
    #pragma unroll
    for (int s = 0; s < 2; s++)
        #pragma unroll
        for (int i = 0; i < 4; i++) acc[s][i] = (f32x4){0.f, 0.f, 0.f, 0.f};

    const int arow0 = (32 * wr + l15) * KPS;
    const int arow1 = arow0 + 16 * KPS;

    // ================= GEMM1: z0 @ W1 (A from LDS, bf16) =================
    #pragma unroll
    for (int kh = 0; kh < 2; kh++) {
        Frag bf[2][4];
        short8 a0[2], a1[2];
        #pragma unroll
        for (int kk = 0; kk < 2; kk++) {
            int ks = kh * 2 + kk;
            #pragma unroll
            for (int i = 0; i < 4; i++) {
                size_t woff = (size_t)(((ks * 8 + wc * 4 + i) * 64 + lane) * 8);
                bf[kk][i].s = *((const short8*)&whi[woff]);
            }
            a0[kk] = *((const short8*)&tpk[arow0 + ks * 32 + quad * 8]);
            a1[kk] = *((const short8*)&tpk[arow1 + ks * 32 + quad * 8]);
        }
        #pragma unroll
        for (int kk = 0; kk < 2; kk++) {
            #pragma unroll
            for (int i = 0; i < 4; i++) {
                acc[0][i] = __builtin_amdgcn_mfma_f32_16x16x32_bf16(a0[kk], bf[kk][i].s, acc[0][i], 0, 0, 0);
                acc[1][i] = __builtin_amdgcn_mfma_f32_16x16x32_bf16(a1[kk], bf[kk][i].s, acc[1][i], 0, 0, 0);
            }
        }
    }
    __syncthreads();

    // ---- bias + relu -> t (bf16) in LDS ----
    #pragma unroll
    for (int i = 0; i < 4; i++) {
        int col = wc * 64 + i * 16 + l15;
        float bb = b1[col];
        #pragma unroll
        for (int s = 0; s < 2; s++) {
            #pragma unroll
            for (int r = 0; r < 4; r++) {
                int m = 32 * wr + 16 * s + quad * 4 + r;
                float v = fmaxf(acc[s][i][r] + bb, 0.f);
                tpk[m * KPS + col] = f2bf(v);
            }
            acc[s][i] = (f32x4){0.f, 0.f, 0.f, 0.f};
        }
    }
    __syncthreads();

    // ================= GEMM2: t @ W2 =================
    const unsigned short* w2 = whi + 16384;
    #pragma unroll
    for (int kh = 0; kh < 2; kh++) {
        Frag bf[2][4];
        short8 a0[2], a1[2];
        #pragma unroll
        for (int kk = 0; kk < 2; kk++) {
            int ks = kh * 2 + kk;
            #pragma unroll
            for (int i = 0; i < 4; i++) {
                size_t woff = (size_t)(((ks * 8 + wc * 4 + i) * 64 + lane) * 8);
                bf[kk][i].s = *((const short8*)&w2[woff]);
            }
            a0[kk] = *((const short8*)&tpk[arow0 + ks * 32 + quad * 8]);
            a1[kk] = *((const short8*)&tpk[arow1 + ks * 32 + quad * 8]);
        }
        #pragma unroll
        for (int kk = 0; kk < 2; kk++) {
            #pragma unroll
            for (int i = 0; i < 4; i++) {
                acc[0][i] = __builtin_amdgcn_mfma_f32_16x16x32_bf16(a0[kk], bf[kk][i].s, acc[0][i], 0, 0, 0);
                acc[1][i] = __builtin_amdgcn_mfma_f32_16x16x32_bf16(a1[kk], bf[kk][i].s, acc[1][i], 0, 0, 0);
            }
        }
    }
    __syncthreads();   // tpk free for z staging

    // ---- bias; z-bf16 tile + stats partials ----
    {
        float colsum[4], colsq[4];
        #pragma unroll
        for (int i = 0; i < 4; i++) {
            int col = wc * 64 + i * 16 + l15;
            float bb = b2[col];
            float su = 0.f, q2 = 0.f;
            #pragma unroll
            for (int s = 0; s < 2; s++) {
                #pragma unroll
                for (int r = 0; r < 4; r++) {
                    int m = 32 * wr + 16 * s + quad * 4 + r;
                    int n = base + m;
                    float v = acc[s][i][r] + bb;
                    tpk[m * KPS + col] = f2bf(v);
                    if (n < N_NODES) { su += v; q2 += v * v; }
                }
            }
            colsum[i] = su; colsq[i] = q2;
        }
        #pragma unroll
        for (int i = 0; i < 4; i++) {
            sums[(w * 4 + i) * 64 + lane] = colsum[i];
            sqs [(w * 4 + i) * 64 + lane] = colsq[i];
        }
    }
    __syncthreads();

    // ---- coalesced z store (interleaved: contiguous 64B per 4-lane group) ----
    {
        int m2 = t >> 2, c2 = t & 3;
        int n2 = base + m2;
        if (n2 < N_NODES) {
            const uint4* srcp = (const uint4*)(tpk + m2 * KPS);
            uint4* dstp = (uint4*)z + (size_t)n2 * 16;
            #pragma unroll
            for (int j = 0; j < 4; j++) dstp[j * 4 + c2] = srcp[j * 4 + c2];
        }
    }
    if (t < 128) {
        int c = t;
        int wcc = c >> 6, ci = (c >> 4) & 3, cl = c & 15;
        float s = 0.f, q2 = 0.f;
        #pragma unroll
        for (int wrr = 0; wrr < 2; wrr++) {
            int ww = wcc * 2 + wrr;
            #pragma unroll
            for (int u = 0; u < 4; u++) {
                int ln = cl + u * 16;
                s  += sums[(ww * 4 + ci) * 64 + ln];
                q2 += sqs [(ww * 4 + ci) * 64 + ln];
            }
        }
        unsafeAtomicAdd(&stats[c], s);
        unsafeAtomicAdd(&stats[128 + c], q2);
    }
}

// ---------------------------------------------------------------------------
// BN apply + ReLU + write h (bf16) + pool; z packed bf16.
// ---------------------------------------------------------------------------
__global__ __launch_bounds__(256) void bnpool_kernel(
    const unsigned int* __restrict__ z, const float* __restrict__ stats,
    const float* __restrict__ gamma, const float* __restrict__ beta,
    const int* __restrict__ gstart, unsigned int* __restrict__ hout,
    float* __restrict__ pools, int layer)
{
    __shared__ float red[8][128];
    const int g = blockIdx.x;
    const int t = threadIdx.x;
    const int q = t & 31, r = t >> 5;
    const int beg = gstart[g], end = gstart[g + 1];

    float4 s  = ((const float4*)stats)[q];
    float4 sq = ((const float4*)stats)[32 + q];
    float4 gm = ((const float4*)gamma)[q];
    float4 bt = ((const float4*)beta)[q];
    const float invN = 1.0f / (float)N_NODES;
    float m, vr;
    float4 scl, sh;
    m = s.x * invN; vr = sq.x * invN - m * m; scl.x = gm.x * rsqrtf(vr + 1e-5f); sh.x = bt.x - m * scl.x;
    m = s.y * invN; vr = sq.y * invN - m * m; scl.y = gm.y * rsqrtf(vr + 1e-5f); sh.y = bt.y - m * scl.y;
    m = s.z * invN; vr = sq.z * invN - m * m; scl.z = gm.z * rsqrtf(vr + 1e-5f); sh.z = bt.z - m * scl.z;
    m = s.w * invN; vr = sq.w * invN - m * m; scl.w = gm.w * rsqrtf(vr + 1e-5f); sh.w = bt.w - m * scl.w;

    float4 acc = {0.f, 0.f, 0.f, 0.f};
    for (int n = beg + r; n < end; n += 8) {
        uint2 zp = ((const uint2*)z)[(size_t)n * 32 + q];
        float4 hv;
        hv.x = fmaxf(bfu_lo(zp.x) * scl.x + sh.x, 0.f);
        hv.y = fmaxf(bfu_hi(zp.x) * scl.y + sh.y, 0.f);
        hv.z = fmaxf(bfu_lo(zp.y) * scl.z + sh.z, 0.f);
        hv.w = fmaxf(bfu_hi(zp.y) * scl.w + sh.w, 0.f);
        uint2 p;
        p.x = (unsigned)f2bf(hv.x) | ((unsigned)f2bf(hv.y) << 16);
        p.y = (unsigned)f2bf(hv.z) | ((unsigned)f2bf(hv.w) << 16);
        ((uint2*)hout)[(size_t)n * 32 + q] = p;
        acc.x += hv.x; acc.y += hv.y; acc.z += hv.z; acc.w += hv.w;
    }
    red[r][q * 4 + 0] = acc.x;
    red[r][q * 4 + 1] = acc.y;
    red[r][q * 4 + 2] = acc.z;
    red[r][q * 4 + 3] = acc.w;
    __syncthreads();
    if (t < 128) {
        float sm = 0.f;
        #pragma unroll
        for (int rr = 0; rr < 8; rr++) sm += red[rr][t];
        pools[(size_t)g * (DIM * NLAYERS) + (size_t)layer * DIM + t] = sm;
    }
}

// ---------------------------------------------------------------------------
// Final linear head: one wave per graph
// ---------------------------------------------------------------------------
__global__ __launch_bounds__(64) void final_kernel(
    const float* __restrict__ pools, const float* __restrict__ Wlin,
    const float* __restrict__ blin, float* __restrict__ out)
{
    int g = blockIdx.x;
    int lane = threadIdx.x;
    const float* xr = pools + (size_t)g * (DIM * NLAYERS);
    float a[NCLASSES];
    #pragma unroll
    for (int o = 0; o < NCLASSES; o++) a[o] = 0.f;
    for (int kk = 0; kk < DIM * NLAYERS; kk += 64) {
        float xv = xr[kk + lane];
        const float* wr = Wlin + (size_t)(kk + lane) * NCLASSES;
        #pragma unroll
        for (int o = 0; o < NCLASSES; o++) a[o] += xv * wr[o];
    }
    #pragma unroll
    for (int o = 0; o < NCLASSES; o++) {
        float v = a[o];
        #pragma unroll
        for (int off = 32; off > 0; off >>= 1) v += __shfl_down(v, off, 64);
        if (lane == 0) out[(size_t)g * NCLASSES + o] = v + blin[o];
    }
}

// ---------------------------------------------------------------------------
extern "C" void kernel_launch(void* const* d_in, const int* in_sizes, int n_in,
                              void* d_out, int out_size, void* d_ws, size_t ws_size,
                              hipStream_t stream)
{
    const float* x     = (const float*)d_in[0];
    const int*   src   = (const int*)d_in[1];
    const int*   dst   = ((const int*)d_in[1]) + N_EDGES;
    const int*   batch = (const int*)d_in[2];
    const float* W1    = (const float*)d_in[3];
    const float* b1    = (const float*)d_in[4];
    const float* W2    = (const float*)d_in[5];
    const float* b2    = (const float*)d_in[6];
    const float* eps   = (const float*)d_in[7];
    const float* gamma = (const float*)d_in[8];
    const float* beta  = (const float*)d_in[9];
    const float* Wlin  = (const float*)d_in[10];
    const float* blin  = (const float*)d_in[11];
    float* out = (float*)d_out;

    char* ws = (char*)d_ws;
    const size_t FEATH = (size_t)N_NODES * DIM * sizeof(unsigned short); // 12.8 MB
    size_t off = 0;
    unsigned int* buf_h = (unsigned int*)(ws + off); off += FEATH;       // bf16 h
    unsigned short* buf_z = (unsigned short*)(ws + off); off += FEATH;   // bf16 z
    float* pools  = (float*)(ws + off); off += (size_t)N_GRAPHS * DIM * NLAYERS * sizeof(float);
    float* stats  = (float*)(ws + off); off += (size_t)NLAYERS * 256 * sizeof(float);
    int*   deg    = (int*)(ws + off);   off += (size_t)N_NODES * sizeof(int);      // also "cursor"
    int*   rowptr = (int*)(ws + off);   off += (size_t)(N_NODES + 1) * sizeof(int) + 12;
    int*   csr    = (int*)(ws + off);   off += (size_t)N_EDGES * sizeof(int);
    int*   gstart = (int*)(ws + off);   off += 2064;
    int*   bsum   = (int*)(ws + off);   off += 208;
    unsigned short* whi = (unsigned short*)(ws + off); off += (size_t)NLAYERS * 2 * 16384 * 2;

    hipMemsetAsync(deg, 0, (size_t)N_NODES * sizeof(int), stream);

    // ---- once per call: CSR chain + fused prep (bounds/xconv/wconv/stats) ----
    hist_kernel<<<(N_EDGES + 255) / 256, 256, 0, stream>>>(dst, deg);
    scan1_kernel<<<49, 256, 0, stream>>>(deg, bsum);
    scan2_kernel<<<1, 64, 0, stream>>>(bsum);
    scan3_kernel<<<49, 256, 0, stream>>>(deg, bsum, rowptr, deg /*cursor*/);
    fill_kernel<<<(N_EDGES + 255) / 256, 256, 0, stream>>>(src, dst, deg, csr);
    prep_kernel<<<6959, 256, 0, stream>>>(batch, gstart, x, buf_h,
                                          W1, W2, whi, stats);

    for (int l = 0; l < NLAYERS; l++) {
        gin_layer_kernel<<<(N_NODES + 63) / 64, 256, 0, stream>>>(
            buf_h, rowptr, csr, eps + l, buf_z,
            whi + (size_t)l * 32768,
            b1 + (size_t)l * DIM, b2 + (size_t)l * DIM,
            stats + (size_t)l * 256);
        bnpool_kernel<<<N_GRAPHS, 256, 0, stream>>>(
            (const unsigned int*)buf_z, stats + (size_t)l * 256,
            gamma + (size_t)l * DIM, beta + (size_t)l * DIM,
            gstart, buf_h, pools, l);
    }
    final_kernel<<<N_GRAPHS, 64, 0, stream>>>(pools, Wlin, blin, out);
}